// Round 2
// baseline (1846.874 us; speedup 1.0000x reference)
//
#include <hip/hip_runtime.h>

// AttentionLayer: B=8 T=256 M=64 D=512 H=8 DK=64.
// v2 (resubmit — round-1 container failure diagnosed as infra flake; full
// bounds/alignment audit passed): x pre-cast to bf16 (stored in d_out
// scratch); 256-thr qkv_attn blocks (one head-group per WG, x frags from L2,
// LDS 34.8KB -> 4 WG/CU); out_proj on the m97 structure (global_load_lds
// width-16 staging). Workspace: 136,314,880 bytes.

typedef unsigned short u16;
typedef short s4v __attribute__((ext_vector_type(4)));
typedef short s8v __attribute__((ext_vector_type(8)));
typedef unsigned short us4 __attribute__((ext_vector_type(4)));
typedef unsigned short us8 __attribute__((ext_vector_type(8)));
typedef __bf16 bf8v __attribute__((ext_vector_type(8)));
typedef float f4v __attribute__((ext_vector_type(4)));
typedef float fl4 __attribute__((ext_vector_type(4)));

#define LQ 68   // q/k/v/P row stride (u16): 136 B = 34 dw == 2 mod 32, conflict-free

static __device__ __forceinline__ u16 f2bf(float f) {
  union { float f; unsigned u; } v;
  v.f = f;
  unsigned r = v.u + 0x7fffu + ((v.u >> 16) & 1u);  // RNE
  return (u16)(r >> 16);
}

union Frag8 { s4v h[2]; s8v v; };

static __device__ __forceinline__ s8v load_frag(const u16* p) {
  // two 8B LDS reads (LQ stride only guarantees 8B alignment)
  Frag8 f;
  f.h[0] = *(const s4v*)(p);
  f.h[1] = *(const s4v*)(p + 4);
  return f.v;
}

static __device__ __forceinline__ f4v mfma16(s8v a, s8v b, f4v c) {
  return __builtin_amdgcn_mfma_f32_16x16x32_bf16(
      __builtin_bit_cast(bf8v, a), __builtin_bit_cast(bf8v, b), c, 0, 0, 0);
}

// async global->LDS, 16B per lane; lds must be wave-uniform (HW adds lane*16)
static __device__ __forceinline__ void gload_lds16(const u16* g, u16* lds) {
  __builtin_amdgcn_global_load_lds(
      (const __attribute__((address_space(1))) void*)g,
      (__attribute__((address_space(3))) void*)lds, 16, 0, 0);
}

// ---------------------------------------------------------------- weights
__global__ __launch_bounds__(256) void pack_weights_kernel(
    const float* __restrict__ Wq, const float* __restrict__ Wk,
    const float* __restrict__ Wv, const float* __restrict__ Wo,
    u16* __restrict__ Wqkv, u16* __restrict__ Wob) {
  const int i4 = (blockIdx.x * 256 + threadIdx.x) * 4;  // 0..262140
  fl4 a = *(const fl4*)(Wq + i4);
  fl4 b = *(const fl4*)(Wk + i4);
  fl4 c = *(const fl4*)(Wv + i4);
  fl4 d = *(const fl4*)(Wo + i4);
  us4 pa, pb, pc, pd;
#pragma unroll
  for (int t = 0; t < 4; ++t) {
    pa[t] = f2bf(a[t]); pb[t] = f2bf(b[t]);
    pc[t] = f2bf(c[t]); pd[t] = f2bf(d[t]);
  }
  *(us4*)(Wqkv + i4) = pa;
  *(us4*)(Wqkv + 262144 + i4) = pb;
  *(us4*)(Wqkv + 524288 + i4) = pc;
  *(us4*)(Wob + i4) = pd;
}

// ---------------------------------------------------------------- x cast
// x fp32 (268MB) -> xb bf16 (134MB, scratch in d_out). 2048 blk x 256 thr x 16.
__global__ __launch_bounds__(256) void xcast_kernel(const float* __restrict__ x,
                                                    u16* __restrict__ xb) {
  const int t = blockIdx.x * 256 + threadIdx.x;  // 0..524287
#pragma unroll
  for (int i = 0; i < 16; ++i) {
    const size_t c8 = ((size_t)i * 524288 + (size_t)t) * 8;
    fl4 v0 = *(const fl4*)(x + c8);
    fl4 v1 = *(const fl4*)(x + c8 + 4);
    us8 p;
#pragma unroll
    for (int j = 0; j < 4; ++j) { p[j] = f2bf(v0[j]); p[4 + j] = f2bf(v1[j]); }
    *(us8*)(xb + c8) = p;
  }
}

// ------------------------------------------------- fused QKV + attention
// grid: 4096 = 2048 (b,t) x 2 head-groups; 256 threads = 4 waves.
// LDS 34,816 B -> 4 WG/CU; launch_bounds(256,4) caps VGPR at 128 for 50% occ.
__global__ __launch_bounds__(256, 4) void qkv_attn_kernel(
    const u16* __restrict__ xb, const u16* __restrict__ Wqkv,
    const float* __restrict__ bq, const float* __restrict__ bk,
    const float* __restrict__ bv, u16* __restrict__ attn) {
  __shared__ u16 qs[64 * LQ];   // q' (scaled+biased)
  __shared__ u16 ks_[64 * LQ];
  __shared__ u16 vs[64 * LQ];   // stored transposed: vs[dk][m]
  __shared__ u16 Ps[64 * LQ];   // softmax probs (layout transform)

  const int bt = blockIdx.x >> 1;
  const int grp = blockIdx.x & 1;  // heads 0..3 / 4..7
  const int tid = threadIdx.x;
  const int lane = tid & 63;
  const int w = tid >> 6;  // strip id (output-col strip / S row strip)
  const int l15 = lane & 15;
  const int l4 = lane >> 4;

  // per-lane base for x A-frags, read straight from global bf16 (L2-resident)
  const u16* xw = xb + (size_t)bt * (64 * 512) + (size_t)l15 * 512 + l4 * 8;
  const f4v fzero = {0.f, 0.f, 0.f, 0.f};

  for (int hi = 0; hi < 4; ++hi) {
    const int h = grp * 4 + hi;
    // ---- QKV GEMM: this wave computes cols [16w,16w+16) of q_h/k_h/v_h ----
    const int ncol = h * 64 + 16 * w + l15;  // global output-neuron index
    const float bqv = bq[ncol];
    const float bkv = bk[ncol];
    const float bvv = bv[ncol];
    const u16* WqP = Wqkv + (size_t)ncol * 512 + l4 * 8;

    f4v aq[4], ak[4], av[4];
#pragma unroll
    for (int i = 0; i < 4; ++i) { aq[i] = fzero; ak[i] = fzero; av[i] = fzero; }

#pragma unroll
    for (int kk = 0; kk < 16; ++kk) {
      const s8v bq8 = *(const s8v*)(WqP + kk * 32);            // L2-hot weights
      const s8v bk8 = *(const s8v*)(WqP + 262144 + kk * 32);
      const s8v bv8 = *(const s8v*)(WqP + 524288 + kk * 32);
      const s8v a0 = *(const s8v*)(xw + kk * 32);              // x frags, L2
      const s8v a1 = *(const s8v*)(xw + 16 * 512 + kk * 32);
      const s8v a2 = *(const s8v*)(xw + 32 * 512 + kk * 32);
      const s8v a3 = *(const s8v*)(xw + 48 * 512 + kk * 32);
      aq[0] = mfma16(a0, bq8, aq[0]); aq[1] = mfma16(a1, bq8, aq[1]);
      aq[2] = mfma16(a2, bq8, aq[2]); aq[3] = mfma16(a3, bq8, aq[3]);
      ak[0] = mfma16(a0, bk8, ak[0]); ak[1] = mfma16(a1, bk8, ak[1]);
      ak[2] = mfma16(a2, bk8, ak[2]); ak[3] = mfma16(a3, bk8, ak[3]);
      av[0] = mfma16(a0, bv8, av[0]); av[1] = mfma16(a1, bv8, av[1]);
      av[2] = mfma16(a2, bv8, av[2]); av[3] = mfma16(a3, bv8, av[3]);
    }

    // epilogue: bias (+ 1/sqrt(DK) folded into q), write bf16 to LDS
    const int nl = 16 * w + l15;
#pragma unroll
    for (int i = 0; i < 4; ++i) {
#pragma unroll
      for (int r = 0; r < 4; ++r) {
        const int m = 16 * i + 4 * l4 + r;  // C-layout row
        qs[m * LQ + nl] = f2bf((aq[i][r] + bqv) * 0.125f);
        ks_[m * LQ + nl] = f2bf(ak[i][r] + bkv);
        vs[nl * LQ + m] = f2bf(av[i][r] + bvv);  // transposed for PV B-frags
      }
    }
    __syncthreads();

    // ---- S = q' k^T : wave owns rows [16w,16w+16), all 64 cols ----
    f4v s[4];
#pragma unroll
    for (int j = 0; j < 4; ++j) s[j] = fzero;
#pragma unroll
    for (int kc = 0; kc < 2; ++kc) {
      const s8v af = load_frag(&qs[(16 * w + l15) * LQ + kc * 32 + l4 * 8]);
#pragma unroll
      for (int j = 0; j < 4; ++j) {
        const s8v bf = load_frag(&ks_[(16 * j + l15) * LQ + kc * 32 + l4 * 8]);
        s[j] = mfma16(af, bf, s[j]);
      }
    }
    // softmax over 64 cols: 4 regs (col-tiles) x 16 lanes of the quad-group
#pragma unroll
    for (int r = 0; r < 4; ++r) {
      float mx = fmaxf(fmaxf(s[0][r], s[1][r]), fmaxf(s[2][r], s[3][r]));
      mx = fmaxf(mx, __shfl_xor(mx, 1));
      mx = fmaxf(mx, __shfl_xor(mx, 2));
      mx = fmaxf(mx, __shfl_xor(mx, 4));
      mx = fmaxf(mx, __shfl_xor(mx, 8));
      float e0 = __expf(s[0][r] - mx);
      float e1 = __expf(s[1][r] - mx);
      float e2 = __expf(s[2][r] - mx);
      float e3 = __expf(s[3][r] - mx);
      float sm = e0 + e1 + e2 + e3;
      sm += __shfl_xor(sm, 1);
      sm += __shfl_xor(sm, 2);
      sm += __shfl_xor(sm, 4);
      sm += __shfl_xor(sm, 8);
      const float inv = __builtin_amdgcn_rcpf(sm);
      s[0][r] = e0 * inv; s[1][r] = e1 * inv;
      s[2][r] = e2 * inv; s[3][r] = e3 * inv;
    }
    // P: C-layout -> LDS (A-layout consumed below)
#pragma unroll
    for (int j = 0; j < 4; ++j)
#pragma unroll
      for (int r = 0; r < 4; ++r)
        Ps[(16 * w + 4 * l4 + r) * LQ + 16 * j + l15] = f2bf(s[j][r]);
    __syncthreads();

    // ---- O = P @ V : rows [16w,16w+16) ----
    f4v o[4];
#pragma unroll
    for (int j = 0; j < 4; ++j) o[j] = fzero;
#pragma unroll
    for (int kc = 0; kc < 2; ++kc) {
      const s8v af = load_frag(&Ps[(16 * w + l15) * LQ + kc * 32 + l4 * 8]);
#pragma unroll
      for (int j = 0; j < 4; ++j) {
        const s8v bf = load_frag(&vs[(16 * j + l15) * LQ + kc * 32 + l4 * 8]);
        o[j] = mfma16(af, bf, o[j]);
      }
    }
    u16* ap = attn + (size_t)(bt * 64) * 512 + h * 64;
#pragma unroll
    for (int j = 0; j < 4; ++j)
#pragma unroll
      for (int r = 0; r < 4; ++r)
        ap[(size_t)(16 * w + 4 * l4 + r) * 512 + 16 * j + l15] = f2bf(o[j][r]);
    __syncthreads();  // protect qs/ks/vs/Ps before next head
  }
}

// ------------------------------------------------- output projection GEMM
// out[131072][512] = attn(bf16) @ Wo^T + bo ; m97 structure: 128x128 tile,
// BK=32, linear LDS, global_load_lds width-16 staging, 2-barrier loop.
__global__ __launch_bounds__(256) void out_proj_kernel(
    const u16* __restrict__ attn, const u16* __restrict__ Wob,
    const float* __restrict__ bo, float* __restrict__ out) {
  __shared__ __align__(16) u16 As[128 * 32];  // 8KB, linear (rows of 64B)
  __shared__ __align__(16) u16 Bs[128 * 32];
  const int m0 = blockIdx.x * 128;
  const int n0 = blockIdx.y * 128;
  const int tid = threadIdx.x;
  const int lane = tid & 63;
  const int wave = tid >> 6;
  const int wy = wave >> 1;
  const int wx = wave & 1;
  const int l15 = lane & 15;
  const int l4 = lane >> 4;

  // staging: wave stages rows [wave*32, wave*32+32) of As and Bs.
  // one gload_lds16 = 64 lanes x 16B = 16 rows; lane l -> row +(l>>2), elems (l&3)*8
  const int r0 = wave * 32;
  const int lrow = lane >> 2;
  const int lcol = (lane & 3) * 8;
  const u16* Ag = attn + (size_t)(m0 + r0 + lrow) * 512 + lcol;
  const u16* Bg = Wob + (size_t)(n0 + r0 + lrow) * 512 + lcol;
  u16* As0 = &As[r0 * 32];
  u16* As1 = &As[(r0 + 16) * 32];
  u16* Bs0 = &Bs[r0 * 32];
  u16* Bs1 = &Bs[(r0 + 16) * 32];

  const f4v fzero = {0.f, 0.f, 0.f, 0.f};
  f4v acc[4][4];
#pragma unroll
  for (int i = 0; i < 4; ++i)
#pragma unroll
    for (int j = 0; j < 4; ++j) acc[i][j] = fzero;

  for (int k0 = 0; k0 < 512; k0 += 32) {
    __syncthreads();  // previous frag reads done before overwrite
    gload_lds16(Ag + k0, As0);
    gload_lds16(Ag + 16 * 512 + k0, As1);
    gload_lds16(Bg + k0, Bs0);
    gload_lds16(Bg + 16 * 512 + k0, Bs1);
    __syncthreads();  // compiler drains vmcnt before s_barrier -> LDS ready
    s8v a[4], b[4];
#pragma unroll
    for (int i = 0; i < 4; ++i)
      a[i] = *(const s8v*)&As[(wy * 64 + 16 * i + l15) * 32 + l4 * 8];
#pragma unroll
    for (int j = 0; j < 4; ++j)
      b[j] = *(const s8v*)&Bs[(wx * 64 + 16 * j + l15) * 32 + l4 * 8];
#pragma unroll
    for (int i = 0; i < 4; ++i)
#pragma unroll
      for (int j = 0; j < 4; ++j)
        acc[i][j] = mfma16(a[i], b[j], acc[i][j]);
  }
#pragma unroll
  for (int j = 0; j < 4; ++j) {
    const int col = n0 + wx * 64 + 16 * j + l15;
    const float bb = bo[col];
#pragma unroll
    for (int i = 0; i < 4; ++i) {
#pragma unroll
      for (int r = 0; r < 4; ++r) {
        const int row = m0 + wy * 64 + 16 * i + 4 * l4 + r;
        out[(size_t)row * 512 + col] = acc[i][j][r] + bb;
      }
    }
  }
}

extern "C" void kernel_launch(void* const* d_in, const int* in_sizes, int n_in,
                              void* d_out, int out_size, void* d_ws, size_t ws_size,
                              hipStream_t stream) {
  const float* x  = (const float*)d_in[0];
  const float* Wq = (const float*)d_in[1];
  const float* bq = (const float*)d_in[2];
  const float* Wk = (const float*)d_in[3];
  const float* bk = (const float*)d_in[4];
  const float* Wv = (const float*)d_in[5];
  const float* bv = (const float*)d_in[6];
  const float* Wo = (const float*)d_in[7];
  const float* bo = (const float*)d_in[8];
  float* out = (float*)d_out;

  // workspace layout (136,314,880 B):
  u16* Wqkv = (u16*)d_ws;              // [1536][512] bf16 = 1,572,864 B
  u16* Wob  = Wqkv + 3 * 512 * 512;    // [512][512]  bf16 =   524,288 B
  u16* attn = Wob + 512 * 512;         // [131072][512] bf16 = 134,217,728 B
  // xb (bf16 x, 134,217,728 B) lives in the first half of d_out (268 MB fp32):
  // consumed by qkv_attn before out_proj overwrites d_out with the result.
  u16* xb = (u16*)d_out;

  pack_weights_kernel<<<256, 256, 0, stream>>>(Wq, Wk, Wv, Wo, Wqkv, Wob);
  xcast_kernel<<<2048, 256, 0, stream>>>(x, xb);
  qkv_attn_kernel<<<4096, 256, 0, stream>>>(xb, Wqkv, bq, bk, bv, attn);
  out_proj_kernel<<<dim3(1024, 4), 256, 0, stream>>>(attn, Wob, bo, out);
}

// Round 3
// 1423.677 us; speedup vs baseline: 1.2973x; 1.2973x over previous
//
#include <hip/hip_runtime.h>

// AttentionLayer: B=8 T=256 M=64 D=512 H=8 DK=64.
// v3: one 1024-thr block (16 waves, 4/SIMD) per (b,t); x staged ONCE into LDS
// via global_load_lds from a pre-swizzled bf16 image (xb, in d_out scratch);
// 4 heads per phase, q/k+P(alias)/v XOR-swizzled (conflict-free, no padding);
// LDS = 160 KiB exactly. attn + Wob stored pre-swizzled so out_proj's
// gload_lds tiles read conflict-free; out_proj BK=64, 4 WG/CU.
// Workspace: 136,314,880 bytes.

typedef unsigned short u16;
typedef short s8v __attribute__((ext_vector_type(8)));
typedef unsigned short us4 __attribute__((ext_vector_type(4)));
typedef unsigned short us8 __attribute__((ext_vector_type(8)));
typedef __bf16 bf8v __attribute__((ext_vector_type(8)));
typedef float f4v __attribute__((ext_vector_type(4)));
typedef float fl4 __attribute__((ext_vector_type(4)));

static __device__ __forceinline__ u16 f2bf(float f) {
  union { float f; unsigned u; } v;
  v.f = f;
  unsigned r = v.u + 0x7fffu + ((v.u >> 16) & 1u);  // RNE
  return (u16)(r >> 16);
}

static __device__ __forceinline__ f4v mfma16(s8v a, s8v b, f4v c) {
  return __builtin_amdgcn_mfma_f32_16x16x32_bf16(
      __builtin_bit_cast(bf8v, a), __builtin_bit_cast(bf8v, b), c, 0, 0, 0);
}

// async global->LDS, 16B/lane; lds base wave-uniform (HW adds lane*16)
static __device__ __forceinline__ void gload_lds16(const u16* g, u16* lds) {
  __builtin_amdgcn_global_load_lds(
      (const __attribute__((address_space(1))) void*)g,
      (__attribute__((address_space(3))) void*)lds, 16, 0, 0);
}

// ---------------------------------------------------------------- weights
// Wqkv linear; Wob stored PRE-SWIZZLED: row n, col k at index k ^ ((n&7)<<3).
__global__ __launch_bounds__(256) void pack_weights_kernel(
    const float* __restrict__ Wq, const float* __restrict__ Wk,
    const float* __restrict__ Wv, const float* __restrict__ Wo,
    u16* __restrict__ Wqkv, u16* __restrict__ Wob) {
  const int i4 = (blockIdx.x * 256 + threadIdx.x) * 4;  // 0..262140
  fl4 a = *(const fl4*)(Wq + i4);
  fl4 b = *(const fl4*)(Wk + i4);
  fl4 c = *(const fl4*)(Wv + i4);
  fl4 d = *(const fl4*)(Wo + i4);
  us4 pa, pb, pc, pd;
#pragma unroll
  for (int t = 0; t < 4; ++t) {
    pa[t] = f2bf(a[t]); pb[t] = f2bf(b[t]);
    pc[t] = f2bf(c[t]); pd[t] = f2bf(d[t]);
  }
  *(us4*)(Wqkv + i4) = pa;
  *(us4*)(Wqkv + 262144 + i4) = pb;
  *(us4*)(Wqkv + 524288 + i4) = pc;
  const int swo = ((i4 >> 9) & 7) << 3;  // row = i4>>9; flips k bits 3..5 only
  *(us4*)(Wob + (i4 ^ swo)) = pd;
}

// ---------------------------------------------------------------- x cast
// x fp32 -> xb bf16 PRE-SWIZZLED image: row r, col c at r*512 + (c ^ ((r&7)<<3)).
// This is exactly the LDS image qkv_attn wants, so gload_lds stages it linearly.
__global__ __launch_bounds__(256) void xcast_kernel(const float* __restrict__ x,
                                                    u16* __restrict__ xb) {
  const int t = blockIdx.x * 256 + threadIdx.x;  // 0..524287
#pragma unroll
  for (int i = 0; i < 16; ++i) {
    const size_t e = (size_t)i * 524288 + (size_t)t;  // 8-elem chunk id
    const int row = (int)(e >> 6);
    const int c0 = ((int)e & 63) * 8;
    fl4 v0 = *(const fl4*)(x + e * 8);
    fl4 v1 = *(const fl4*)(x + e * 8 + 4);
    us8 p;
#pragma unroll
    for (int j = 0; j < 4; ++j) { p[j] = f2bf(v0[j]); p[4 + j] = f2bf(v1[j]); }
    *(us8*)(xb + (size_t)row * 512 + (c0 ^ ((row & 7) << 3))) = p;
  }
}

// ------------------------------------------------- fused QKV + attention
// grid: 2048 (one WG per (b,t)); 1024 threads = 16 waves = 4 waves/SIMD.
// Two phases (g=0,1) of 4 heads each. Per phase: 16 waves each compute one
// 16-col strip of q,k,v (v1's proven 12-MFMA/kk inner loop), then wave w
// does attention for (head w>>2, row-strip w&3).
__global__ __launch_bounds__(1024) void qkv_attn_kernel(
    const u16* __restrict__ xb, const u16* __restrict__ Wqkv,
    const float* __restrict__ bq, const float* __restrict__ bk,
    const float* __restrict__ bv, u16* __restrict__ attn) {
  __shared__ __align__(16) u16 x_s[64 * 512];    // 65536 B, swizzled image
  __shared__ __align__(16) u16 qs[4 * 64 * 64];  // 32768 B, [h][m][c^sw(m)]
  __shared__ __align__(16) u16 kp[4 * 64 * 64];  // K, then P (aliased)
  __shared__ __align__(16) u16 vs[4 * 64 * 64];  // V transposed [h][d][m^sw(d)]
  // total 163,840 B = 160 KiB exactly (AITER precedent on gfx950)

  const int bt = blockIdx.x;
  const int tid = threadIdx.x;
  const int lane = tid & 63;
  const int w = tid >> 6;        // 0..15
  const int l15 = lane & 15;
  const int l4 = lane >> 4;
  const int hi = w >> 2;         // head within phase
  const int ws = w & 3;          // row-strip for attention
  const int swl = (l15 & 7) << 3;  // frag-read swizzle (rows ≡ l15 mod 8)

  // stage x_bt (pre-swizzled) -> x_s: each gload = 1 row (512 u16 = 1 KB)
  {
    const u16* src = xb + (size_t)bt * 32768 + w * 2048 + lane * 8;
    u16* dst = x_s + w * 2048;
    gload_lds16(src, dst);
    gload_lds16(src + 512, dst + 512);
    gload_lds16(src + 1024, dst + 1024);
    gload_lds16(src + 1536, dst + 1536);
  }
  __syncthreads();

  const f4v fzero = {0.f, 0.f, 0.f, 0.f};

  for (int g = 0; g < 2; ++g) {
    // ---- QKV GEMM: wave w computes cols [16w,16w+16) of the 256-col block ----
    const int nl = 16 * w + l15;          // 0..255
    const int ncol = g * 256 + nl;        // global output-neuron index
    const float bqv = bq[ncol];
    const float bkv = bk[ncol];
    const float bvv = bv[ncol];
    const u16* WqP = Wqkv + (size_t)ncol * 512 + l4 * 8;

    f4v aq[4], ak[4], av[4];
#pragma unroll
    for (int i = 0; i < 4; ++i) { aq[i] = fzero; ak[i] = fzero; av[i] = fzero; }

#pragma unroll
    for (int kk = 0; kk < 16; ++kk) {
      const int ko = (kk * 32 + l4 * 8) ^ swl;                 // swizzled, 16B-aligned
      const s8v bq8 = *(const s8v*)(WqP + kk * 32);            // L2-hot weights
      const s8v bk8 = *(const s8v*)(WqP + 262144 + kk * 32);
      const s8v bv8 = *(const s8v*)(WqP + 524288 + kk * 32);
      const s8v a0 = *(const s8v*)&x_s[(0 + l15) * 512 + ko];  // single b128 each
      const s8v a1 = *(const s8v*)&x_s[(16 + l15) * 512 + ko];
      const s8v a2 = *(const s8v*)&x_s[(32 + l15) * 512 + ko];
      const s8v a3 = *(const s8v*)&x_s[(48 + l15) * 512 + ko];
      aq[0] = mfma16(a0, bq8, aq[0]); aq[1] = mfma16(a1, bq8, aq[1]);
      aq[2] = mfma16(a2, bq8, aq[2]); aq[3] = mfma16(a3, bq8, aq[3]);
      ak[0] = mfma16(a0, bk8, ak[0]); ak[1] = mfma16(a1, bk8, ak[1]);
      ak[2] = mfma16(a2, bk8, ak[2]); ak[3] = mfma16(a3, bk8, ak[3]);
      av[0] = mfma16(a0, bv8, av[0]); av[1] = mfma16(a1, bv8, av[1]);
      av[2] = mfma16(a2, bv8, av[2]); av[3] = mfma16(a3, bv8, av[3]);
    }

    // epilogue: bias (+ 1/8 folded into q), write swizzled bf16 to LDS
    {
      const int hq = nl >> 6;        // head these cols belong to (= w>>2)
      const int ch = nl & 63;        // col within head
      u16* qh = qs + hq * 4096;
      u16* kh = kp + hq * 4096;
      u16* vh = vs + hq * 4096;
      const int swv = (ch & 7) << 3;  // vs row = d = ch
#pragma unroll
      for (int i = 0; i < 4; ++i) {
#pragma unroll
        for (int r = 0; r < 4; ++r) {
          const int m = 16 * i + 4 * l4 + r;  // C-layout row
          const int sm = (m & 7) << 3;
          qh[m * 64 + (ch ^ sm)] = f2bf((aq[i][r] + bqv) * 0.125f);
          kh[m * 64 + (ch ^ sm)] = f2bf(ak[i][r] + bkv);
          vh[ch * 64 + (m ^ swv)] = f2bf(av[i][r] + bvv);  // transposed
        }
      }
    }
    __syncthreads();

    // ---- S = q' k^T : wave w -> head hi, rows [16ws,16ws+16), all 64 cols ----
    f4v s[4];
#pragma unroll
    for (int j = 0; j < 4; ++j) s[j] = fzero;
    {
      const u16* qrow = qs + hi * 4096 + (16 * ws + l15) * 64;
      const u16* kh = kp + hi * 4096;
#pragma unroll
      for (int kc = 0; kc < 2; ++kc) {
        const int co = (kc * 32 + l4 * 8) ^ swl;
        const s8v af = *(const s8v*)(qrow + co);
#pragma unroll
        for (int j = 0; j < 4; ++j) {
          const s8v bf = *(const s8v*)(kh + (16 * j + l15) * 64 + co);
          s[j] = mfma16(af, bf, s[j]);
        }
      }
    }
    // softmax over 64 cols (k = 16j + l15): in-lane over j, shfl over l15 group
#pragma unroll
    for (int r = 0; r < 4; ++r) {
      float mx = fmaxf(fmaxf(s[0][r], s[1][r]), fmaxf(s[2][r], s[3][r]));
      mx = fmaxf(mx, __shfl_xor(mx, 1));
      mx = fmaxf(mx, __shfl_xor(mx, 2));
      mx = fmaxf(mx, __shfl_xor(mx, 4));
      mx = fmaxf(mx, __shfl_xor(mx, 8));
      float e0 = __expf(s[0][r] - mx);
      float e1 = __expf(s[1][r] - mx);
      float e2 = __expf(s[2][r] - mx);
      float e3 = __expf(s[3][r] - mx);
      float sm = e0 + e1 + e2 + e3;
      sm += __shfl_xor(sm, 1);
      sm += __shfl_xor(sm, 2);
      sm += __shfl_xor(sm, 4);
      sm += __shfl_xor(sm, 8);
      const float inv = __builtin_amdgcn_rcpf(sm);
      s[0][r] = e0 * inv; s[1][r] = e1 * inv;
      s[2][r] = e2 * inv; s[3][r] = e3 * inv;
    }
    __syncthreads();  // all S-reads of kp (K) done -> safe to overwrite with P

    // P: C-layout -> swizzled A-layout, aliased over K
#pragma unroll
    for (int j = 0; j < 4; ++j) {
#pragma unroll
      for (int r = 0; r < 4; ++r) {
        const int m = 16 * ws + 4 * l4 + r;
        kp[hi * 4096 + m * 64 + ((16 * j + l15) ^ ((m & 7) << 3))] = f2bf(s[j][r]);
      }
    }
    __syncthreads();

    // ---- O = P @ V ----
    f4v o[4];
#pragma unroll
    for (int j = 0; j < 4; ++j) o[j] = fzero;
    {
      const u16* prow = kp + hi * 4096 + (16 * ws + l15) * 64;
      const u16* vh = vs + hi * 4096;
#pragma unroll
      for (int kc = 0; kc < 2; ++kc) {
        const int co = (kc * 32 + l4 * 8) ^ swl;
        const s8v af = *(const s8v*)(prow + co);
#pragma unroll
        for (int j = 0; j < 4; ++j) {
          const s8v bf = *(const s8v*)(vh + (16 * j + l15) * 64 + co);
          o[j] = mfma16(af, bf, o[j]);
        }
      }
    }
    // attn write, PRE-SWIZZLED within each head's 64-col block (for out_proj)
    {
      const int hgl = g * 4 + hi;
      u16* ap = attn + (size_t)(bt * 64) * 512 + hgl * 64;
#pragma unroll
      for (int j = 0; j < 4; ++j) {
#pragma unroll
        for (int r = 0; r < 4; ++r) {
          const int m = 16 * ws + 4 * l4 + r;
          ap[(size_t)m * 512 + ((16 * j + l15) ^ ((m & 7) << 3))] = f2bf(o[j][r]);
        }
      }
    }
    __syncthreads();  // protect qs/kp/vs before next phase's epilogue
  }
}

// ------------------------------------------------- output projection GEMM
// out[131072][512] = attn(bf16,swz) @ Wo^T + bo ; 128x128 tiles, BK=64,
// gload_lds staging (sources pre-swizzled -> conflict-free b128 frag reads).
__global__ __launch_bounds__(256) void out_proj_kernel(
    const u16* __restrict__ attn, const u16* __restrict__ Wob,
    const float* __restrict__ bo, float* __restrict__ out) {
  __shared__ __align__(16) u16 As[128 * 64];  // 16 KB, row-major [row][64]
  __shared__ __align__(16) u16 Bs[128 * 64];
  const int m0 = blockIdx.x * 128;
  const int n0 = blockIdx.y * 128;
  const int tid = threadIdx.x;
  const int lane = tid & 63;
  const int wave = tid >> 6;
  const int wy = wave >> 1;
  const int wx = wave & 1;
  const int l15 = lane & 15;
  const int l4 = lane >> 4;
  const int swl = (l15 & 7) << 3;

  // staging: wave stages rows [32w,32w+32); one gload = 8 rows (128 B each)
  const int srow = wave * 32 + (lane >> 3);
  const int scol = (lane & 7) * 8;
  const u16* Ag = attn + (size_t)(m0 + srow) * 512 + scol;
  const u16* Bg = Wob + (size_t)(n0 + srow) * 512 + scol;
  u16* Asw = As + wave * 32 * 64;
  u16* Bsw = Bs + wave * 32 * 64;

  const f4v fzero = {0.f, 0.f, 0.f, 0.f};
  f4v acc[4][4];
#pragma unroll
  for (int i = 0; i < 4; ++i)
#pragma unroll
    for (int j = 0; j < 4; ++j) acc[i][j] = fzero;

  for (int k0 = 0; k0 < 512; k0 += 64) {
    __syncthreads();  // previous frag reads done before overwrite
    gload_lds16(Ag + k0, Asw);
    gload_lds16(Ag + 4096 + k0, Asw + 512);
    gload_lds16(Ag + 8192 + k0, Asw + 1024);
    gload_lds16(Ag + 12288 + k0, Asw + 1536);
    gload_lds16(Bg + k0, Bsw);
    gload_lds16(Bg + 4096 + k0, Bsw + 512);
    gload_lds16(Bg + 8192 + k0, Bsw + 1024);
    gload_lds16(Bg + 12288 + k0, Bsw + 1536);
    __syncthreads();  // compiler drains vmcnt before s_barrier -> LDS ready
#pragma unroll
    for (int kc = 0; kc < 2; ++kc) {
      const int co = (kc * 32 + l4 * 8) ^ swl;
      s8v a[4], b[4];
#pragma unroll
      for (int i = 0; i < 4; ++i)
        a[i] = *(const s8v*)&As[(wy * 64 + 16 * i + l15) * 64 + co];
#pragma unroll
      for (int j = 0; j < 4; ++j)
        b[j] = *(const s8v*)&Bs[(wx * 64 + 16 * j + l15) * 64 + co];
#pragma unroll
      for (int i = 0; i < 4; ++i)
#pragma unroll
        for (int j = 0; j < 4; ++j)
          acc[i][j] = mfma16(a[i], b[j], acc[i][j]);
    }
  }
#pragma unroll
  for (int j = 0; j < 4; ++j) {
    const int col = n0 + wx * 64 + 16 * j + l15;
    const float bb = bo[col];
#pragma unroll
    for (int i = 0; i < 4; ++i) {
#pragma unroll
      for (int r = 0; r < 4; ++r) {
        const int row = m0 + wy * 64 + 16 * i + 4 * l4 + r;
        out[(size_t)row * 512 + col] = acc[i][j][r] + bb;
      }
    }
  }
}

extern "C" void kernel_launch(void* const* d_in, const int* in_sizes, int n_in,
                              void* d_out, int out_size, void* d_ws, size_t ws_size,
                              hipStream_t stream) {
  const float* x  = (const float*)d_in[0];
  const float* Wq = (const float*)d_in[1];
  const float* bq = (const float*)d_in[2];
  const float* Wk = (const float*)d_in[3];
  const float* bk = (const float*)d_in[4];
  const float* Wv = (const float*)d_in[5];
  const float* bv = (const float*)d_in[6];
  const float* Wo = (const float*)d_in[7];
  const float* bo = (const float*)d_in[8];
  float* out = (float*)d_out;

  // workspace layout (136,314,880 B):
  u16* Wqkv = (u16*)d_ws;              // [1536][512] bf16 = 1,572,864 B
  u16* Wob  = Wqkv + 3 * 512 * 512;    // [512][512]  bf16 (swizzled) = 524,288 B
  u16* attn = Wob + 512 * 512;         // [131072][512] bf16 (swizzled) = 134,217,728 B
  // xb (pre-swizzled bf16 x image, 134,217,728 B) lives in d_out's first half;
  // consumed by qkv_attn before out_proj overwrites d_out with the result.
  u16* xb = (u16*)d_out;

  pack_weights_kernel<<<256, 256, 0, stream>>>(Wq, Wk, Wv, Wo, Wqkv, Wob);
  xcast_kernel<<<2048, 256, 0, stream>>>(x, xb);
  qkv_attn_kernel<<<2048, 1024, 0, stream>>>(xb, Wqkv, bq, bk, bv, attn);
  out_proj_kernel<<<dim3(1024, 4), 256, 0, stream>>>(attn, Wob, bo, out);
}